// Round 20
// baseline (165.786 us; speedup 1.0000x reference)
//
#include <hip/hip_runtime.h>

typedef float  f4    __attribute__((ext_vector_type(4)));
typedef float  f32x4 __attribute__((ext_vector_type(4)));
typedef short  s16x8 __attribute__((ext_vector_type(8)));
typedef unsigned int u32x4 __attribute__((ext_vector_type(4)));

#define L_SEQ 2048
#define D4    16
#define NC4   512
#define RAD   128
#define NBH   48
#define TI    32
#define KROWS 288              // staged K rows = window cols [i0-128, i0+160)
#define HSTR  296              // band-buffer row stride in ushort (74 uint2)
#define NPB   6                // tiles (bh values) per persistent block
#define GRID  512              // 2 blocks/CU

// R15 compute-then-sweep, software-pipelined across tiles (R20).
// Persistent block bid handles tiles (bh = 6*(bid&7)+k, i0 = (bid>>3)*32)
// for k = 0..5: the global loads for tile k+1 issue BEFORE the sweep of
// tile k, so their latency hides under ~10us of pure stores; only the
// pack+MFMA+dump (~1us) remains exposed per iteration, vs a full
// stage+MFMA prologue per block in R15. Since dispatch round-robins XCDs
// by bid%8, each XCD's 64 blocks share the same 6 bh values -> K/Q stay
// L2-resident per iteration. All phase internals are R15 verbatim.

__device__ __forceinline__ unsigned bf16rne(float f) {
    unsigned u = __float_as_uint(f);
    return (u + 0x7FFFu + ((u >> 16) & 1u)) >> 16;   // round-to-nearest-even
}

__global__ __launch_bounds__(256, 2)
void band_pipe(const float* __restrict__ Qg, const float* __restrict__ Kg,
               float* __restrict__ outg)
{
    // K rows as 8 16B-units (8 bf16, d-ascending); slot = si*8 + (u ^ (si&7))
    __shared__ u32x4 sK[KROWS * 8];            // 36864 B
    __shared__ unsigned short sH[TI * HSTR];   // 18944 B (total 55808 -> 2 blocks/CU)

    const int t   = threadIdx.x;
    const int bid = blockIdx.x;
    const int xg  = bid & 7;                   // XCD group -> bh base 6*xg
    const int i0  = (bid >> 3) * TI;           // fixed row slab for this block
    const int i04 = i0 >> 2;
    const int kbase = i0 - RAD;

    const int wv = t >> 6, l = t & 63, m = l & 15, g = l >> 4;
    const int rt = wv & 1;                     // row-tile; wave pair splits col-tiles
    const int ib = i0 + 16 * rt;

    f4 kr[18];   // held K staging loads (static indices only)
    f4 qr[4];    // held Q fragment loads
    s16x8 A1, A2;

    auto issue_loads = [&](int bh) {           // no waitcnt here: consumed by pack()
        const f4* __restrict__ K4 = reinterpret_cast<const f4*>(Kg) + (size_t)bh * L_SEQ * D4;
        const f4* __restrict__ Q4 = reinterpret_cast<const f4*>(Qg) + (size_t)bh * L_SEQ * D4;
#pragma unroll
        for (int itr = 0; itr < 9; ++itr) {
            const int s  = itr * 256 + t;
            const int si = s >> 3, u = s & 7;
            int row = kbase + si;
            row = row < 0 ? 0 : (row > L_SEQ - 1 ? L_SEQ - 1 : row);  // clamp; masked at dump
            kr[2 * itr]     = K4[(size_t)row * D4 + 2 * u];
            kr[2 * itr + 1] = K4[(size_t)row * D4 + 2 * u + 1];
        }
        const size_t qb = (size_t)(ib + m) * D4;
        qr[0] = Q4[qb + 2 * g];
        qr[1] = Q4[qb + 2 * g + 1];
        qr[2] = Q4[qb + 8 + 2 * g];
        qr[3] = Q4[qb + 8 + 2 * g + 1];
    };

    auto pack = [&]() {                        // regs -> sK (swizzled) + A-frags
#pragma unroll
        for (int itr = 0; itr < 9; ++itr) {
            const int s  = itr * 256 + t;
            const int si = s >> 3, u = s & 7;
            u32x4 w;
            w.x = bf16rne(kr[2*itr].x)     | (bf16rne(kr[2*itr].y)     << 16);
            w.y = bf16rne(kr[2*itr].z)     | (bf16rne(kr[2*itr].w)     << 16);
            w.z = bf16rne(kr[2*itr+1].x)   | (bf16rne(kr[2*itr+1].y)   << 16);
            w.w = bf16rne(kr[2*itr+1].z)   | (bf16rne(kr[2*itr+1].w)   << 16);
            sK[si * 8 + (u ^ (si & 7))] = w;
        }
        u32x4 wa, wb;
        wa.x = bf16rne(qr[0].x) | (bf16rne(qr[0].y) << 16);
        wa.y = bf16rne(qr[0].z) | (bf16rne(qr[0].w) << 16);
        wa.z = bf16rne(qr[1].x) | (bf16rne(qr[1].y) << 16);
        wa.w = bf16rne(qr[1].z) | (bf16rne(qr[1].w) << 16);
        wb.x = bf16rne(qr[2].x) | (bf16rne(qr[2].y) << 16);
        wb.y = bf16rne(qr[2].z) | (bf16rne(qr[2].w) << 16);
        wb.z = bf16rne(qr[3].x) | (bf16rne(qr[3].y) << 16);
        wb.w = bf16rne(qr[3].z) | (bf16rne(qr[3].w) << 16);
        A1 = __builtin_bit_cast(s16x8, wa);
        A2 = __builtin_bit_cast(s16x8, wb);
    };

    auto mfma_dump = [&]() {                   // sK -> MFMA -> band-mask -> sH
        const int ilb = 16 * rt + 4 * g;
#pragma unroll 1
        for (int k = 0; k < 9; ++k) {
            const int c  = (wv >> 1) + 2 * k;           // col-tile 0..17
            const int si = 16 * c + m;
            const u32x4 b1 = sK[si * 8 + ((g    ) ^ (si & 7))];
            const u32x4 b2 = sK[si * 8 + ((4 + g) ^ (si & 7))];
            f32x4 acc = {0.f, 0.f, 0.f, 0.f};
            acc = __builtin_amdgcn_mfma_f32_16x16x32_bf16(A1, __builtin_bit_cast(s16x8, b1), acc, 0, 0, 0);
            acc = __builtin_amdgcn_mfma_f32_16x16x32_bf16(A2, __builtin_bit_cast(s16x8, b2), acc, 0, 0, 0);
            const int j = kbase + si;                   // global col (C col = lane&15)
#pragma unroll
            for (int r = 0; r < 4; ++r) {
                const int i = i0 + ilb + r;             // C row = 4*(lane>>4)+reg
                const float v = ((unsigned)(i - j + RAD) <= 2u * RAD) ? acc[r] : 0.f;
                sH[(ilb + r) * HSTR + si] = (unsigned short)bf16rne(v);
            }
        }
    };

    auto sweep = [&](int bh) {                 // merged linear full-row sweep (R15)
        f4* __restrict__ O4 = reinterpret_cast<f4*>(outg) + (size_t)bh * L_SEQ * NC4;
        const uint2* sU2 = reinterpret_cast<const uint2*>(sH);
        const int clo  = i04 - 32 < 0 ? 0 : i04 - 32;   // window chunk range
        const int chi  = i04 + 40 > NC4 ? NC4 : i04 + 40;
        const int base = i04 - 32;
#pragma unroll 1
        for (int rr = 0; rr < 8; ++rr) {
            const int il = wv * 8 + rr;                 // local row 0..31
            f4* rowp = O4 + (size_t)(i0 + il) * NC4;
            const int ub = il * (HSTR / 4);             // uint2 row base = il*74
#pragma unroll
            for (int kk = 0; kk < 8; ++kk) {
                const int ch = kk * 64 + l;             // chunk 0..511, coalesced
                int off = ch - base;
                off = off < 0 ? 0 : (off > 71 ? 71 : off);
                const uint2 w = sU2[ub + off];
                f4 v;
                v.x = __uint_as_float(w.x << 16);
                v.y = __uint_as_float(w.x & 0xffff0000u);
                v.z = __uint_as_float(w.y << 16);
                v.w = __uint_as_float(w.y & 0xffff0000u);
                if (!((ch >= clo) & (ch < chi))) v = f4{0.f, 0.f, 0.f, 0.f};
                rowp[ch] = v;
            }
        }
    };

    // ---- prologue: stage + MFMA for tile 0 (bh = 6*xg)
    issue_loads(6 * xg);
    pack();
    __syncthreads();
    mfma_dump();
    __syncthreads();

    // ---- pipelined loop: loads(k+1) || sweep(k), then pack/MFMA(k+1)
#pragma unroll 1
    for (int k = 0; k < NPB; ++k) {
        if (k < NPB - 1) issue_loads(6 * xg + k + 1);
        sweep(6 * xg + k);
        if (k < NPB - 1) {
            pack();                 // writes sK (dead since mfma_dump(k)); sweep reads sH only
            __syncthreads();        // all waves: pack done (sK ready) AND sweep done (sH free)
            mfma_dump();
            __syncthreads();        // sH ready for next sweep
        }
    }
}

extern "C" void kernel_launch(void* const* d_in, const int* in_sizes, int n_in,
                              void* d_out, int out_size, void* d_ws, size_t ws_size,
                              hipStream_t stream) {
    const float* Q = (const float*)d_in[0];
    const float* K = (const float*)d_in[1];
    float* out = (float*)d_out;
    band_pipe<<<GRID, 256, 0, stream>>>(Q, K, out);
}

// Round 21
// 143.973 us; speedup vs baseline: 1.1515x; 1.1515x over previous
//
#include <hip/hip_runtime.h>

typedef float  f4    __attribute__((ext_vector_type(4)));
typedef float  f32x4 __attribute__((ext_vector_type(4)));
typedef short  s16x8 __attribute__((ext_vector_type(8)));
typedef unsigned int u32x4 __attribute__((ext_vector_type(4)));

#define L_SEQ 2048
#define D4    16
#define NC4   512
#define RAD   128
#define NBH   48
#define TI    32
#define NTIL  (L_SEQ / TI)     // 64
#define NBLK  (NBH * NTIL)     // 3072
#define KROWS 288              // staged K rows = window cols [i0-128, i0+160)
#define HSTR  296              // band-buffer row stride in ushort (74 uint2)

// R15 champion (160.3us) + ONE diff: phase-3 sweep stores are nontemporal.
// The 805MB output stream is write-once; plain stores write-allocate through
// L2, churning all 32MB and evicting the K/Q inputs each block re-reads.
// nt stores keep inputs L2-resident and reduce dirty-line management.
//  Phase 1: stage K window as bf16 in LDS (swizzled, proven layout).
//  Phase 2: MFMA 2 row-tiles x 18 col-tiles -> band-masked bf16 into sH.
//  Phase 3: every wave writes 8 COMPLETE rows linearly (1KB/wave-inst),
//           merging zeros with band values from LDS -- now via nt stores.

__device__ __forceinline__ unsigned bf16rne(float f) {
    unsigned u = __float_as_uint(f);
    return (u + 0x7FFFu + ((u >> 16) & 1u)) >> 16;   // round-to-nearest-even
}

__global__ __launch_bounds__(256, 2)
void band_sweep(const float* __restrict__ Qg, const float* __restrict__ Kg,
                float* __restrict__ outg)
{
    // K rows as 8 16B-units (8 bf16, d-ascending); slot = si*8 + (u ^ (si&7))
    __shared__ u32x4 sK[KROWS * 8];            // 36864 B
    __shared__ unsigned short sH[TI * HSTR];   // 18944 B (total 55808 -> 2 blocks/CU)

    const int t  = threadIdx.x;
    const int id = blockIdx.x;
    // bijective XCD swizzle (NBLK % 8 == 0)
    const int swz = (id & 7) * (NBLK / 8) + (id >> 3);
    const int bh  = swz >> 6;
    const int i0  = (swz & (NTIL - 1)) * TI;
    const int i04 = i0 >> 2;

    const f4* __restrict__ K4 = reinterpret_cast<const f4*>(Kg) + (size_t)bh * L_SEQ * D4;
    const f4* __restrict__ Q4 = reinterpret_cast<const f4*>(Qg) + (size_t)bh * L_SEQ * D4;
    f4* __restrict__ O4       = reinterpret_cast<f4*>(outg)     + (size_t)bh * L_SEQ * NC4;

    const int kbase = i0 - RAD;

    // ---- phase 1: stage K rows [i0-128, i0+160) as bf16: 2304 units, 9/thread
#pragma unroll 3
    for (int itr = 0; itr < 9; ++itr) {
        const int s  = itr * 256 + t;
        const int si = s >> 3, u = s & 7;
        int row = kbase + si;
        row = row < 0 ? 0 : (row > L_SEQ - 1 ? L_SEQ - 1 : row);  // clamp; masked at dump
        const f4 a = K4[(size_t)row * D4 + 2 * u];
        const f4 b = K4[(size_t)row * D4 + 2 * u + 1];
        u32x4 w;
        w.x = bf16rne(a.x) | (bf16rne(a.y) << 16);
        w.y = bf16rne(a.z) | (bf16rne(a.w) << 16);
        w.z = bf16rne(b.x) | (bf16rne(b.y) << 16);
        w.w = bf16rne(b.z) | (bf16rne(b.w) << 16);
        sK[si * 8 + (u ^ (si & 7))] = w;
    }

    const int wv = t >> 6, l = t & 63, m = l & 15, g = l >> 4;
    const int rt = wv & 1;              // row-tile (0/1); wave pair splits col-tiles
    const int ib = i0 + 16 * rt;

    // Q A-frags (issued after staging loads; latency hides under the drain)
    s16x8 A1, A2;
    {
        const size_t qb = (size_t)(ib + m) * D4;
        const f4 qa = Q4[qb + 2 * g];
        const f4 qv = Q4[qb + 2 * g + 1];
        const f4 qc = Q4[qb + 8 + 2 * g];
        const f4 qd = Q4[qb + 8 + 2 * g + 1];
        u32x4 wa, wb;
        wa.x = bf16rne(qa.x) | (bf16rne(qa.y) << 16);
        wa.y = bf16rne(qa.z) | (bf16rne(qa.w) << 16);
        wa.z = bf16rne(qv.x) | (bf16rne(qv.y) << 16);
        wa.w = bf16rne(qv.z) | (bf16rne(qv.w) << 16);
        wb.x = bf16rne(qc.x) | (bf16rne(qc.y) << 16);
        wb.y = bf16rne(qc.z) | (bf16rne(qc.w) << 16);
        wb.z = bf16rne(qd.x) | (bf16rne(qd.y) << 16);
        wb.w = bf16rne(qd.z) | (bf16rne(qd.w) << 16);
        A1 = __builtin_bit_cast(s16x8, wa);
        A2 = __builtin_bit_cast(s16x8, wb);
    }
    __syncthreads();

    // ---- phase 2: MFMA -> band-masked bf16 values into sH
    {
        const int ilb = 16 * rt + 4 * g;
#pragma unroll 1
        for (int k = 0; k < 9; ++k) {
            const int c  = (wv >> 1) + 2 * k;           // col-tile 0..17
            const int si = 16 * c + m;
            const u32x4 b1 = sK[si * 8 + ((g    ) ^ (si & 7))];
            const u32x4 b2 = sK[si * 8 + ((4 + g) ^ (si & 7))];
            f32x4 acc = {0.f, 0.f, 0.f, 0.f};
            acc = __builtin_amdgcn_mfma_f32_16x16x32_bf16(A1, __builtin_bit_cast(s16x8, b1), acc, 0, 0, 0);
            acc = __builtin_amdgcn_mfma_f32_16x16x32_bf16(A2, __builtin_bit_cast(s16x8, b2), acc, 0, 0, 0);
            const int j = kbase + si;                   // global col (C col = lane&15)
#pragma unroll
            for (int r = 0; r < 4; ++r) {
                const int i = i0 + ilb + r;             // C row = 4*(lane>>4)+reg
                const float v = ((unsigned)(i - j + RAD) <= 2u * RAD) ? acc[r] : 0.f;
                sH[(ilb + r) * HSTR + si] = (unsigned short)bf16rne(v);
            }
        }
    }
    __syncthreads();

    // ---- phase 3: linear full-row sweep (zeros + band), nt stores, 1KB/wave-inst
    {
        const uint2* sU2 = reinterpret_cast<const uint2*>(sH);
        const int clo  = i04 - 32 < 0 ? 0 : i04 - 32;   // window chunk range
        const int chi  = i04 + 40 > NC4 ? NC4 : i04 + 40;
        const int base = i04 - 32;                      // chunk -> band-col offset
#pragma unroll 1
        for (int rr = 0; rr < 8; ++rr) {
            const int il = wv * 8 + rr;                 // local row 0..31
            f4* rowp = O4 + (size_t)(i0 + il) * NC4;
            const int ub = il * (HSTR / 4);             // uint2 row base = il*74
#pragma unroll
            for (int kk = 0; kk < 8; ++kk) {
                const int ch = kk * 64 + l;             // chunk 0..511, coalesced
                int off = ch - base;
                off = off < 0 ? 0 : (off > 71 ? 71 : off);   // clamp; selected below
                const uint2 w = sU2[ub + off];
                f4 v;
                v.x = __uint_as_float(w.x << 16);
                v.y = __uint_as_float(w.x & 0xffff0000u);
                v.z = __uint_as_float(w.y << 16);
                v.w = __uint_as_float(w.y & 0xffff0000u);
                if (!((ch >= clo) & (ch < chi))) v = f4{0.f, 0.f, 0.f, 0.f};
                __builtin_nontemporal_store(v, rowp + ch);
            }
        }
    }
}

extern "C" void kernel_launch(void* const* d_in, const int* in_sizes, int n_in,
                              void* d_out, int out_size, void* d_ws, size_t ws_size,
                              hipStream_t stream) {
    const float* Q = (const float*)d_in[0];
    const float* K = (const float*)d_in[1];
    float* out = (float*)d_out;
    band_sweep<<<NBLK, 256, 0, stream>>>(Q, K, out);
}